// Round 12
// baseline (241.887 us; speedup 1.0000x reference)
//
#include <hip/hip_runtime.h>

// HungarianMatcher on MI355X (gfx950).
// Output 0: C (16, 1024, 1536) fp32 cost matrix.
// Output 1: matched_query (16, 96) written as fp32 values.
//
// R9: R6c/R7/R8 all land 75-80us fused despite totally different row-cost
// data paths -> tail is dominated by machinery common to all three:
//  (a) lane-0 serial greedy (96 dependent ~120cy LDS round-trips ~ 10-14us)
//  (b) per-iteration serial 16-elem linear min-scan (loop-carried lbv chain).
// Fix: revert to R6c's fastest inner loop (direct coalesced tws read, no
// barriers), parallelize greedy via LDS atomicMin (first-t-wins == min-t per
// column; exact), tree-min (depth 4, (val,idx) tie-break preserving first-k).
// C-write path unchanged (8 rows/blk, NT stores, ~13.6KB static LDS).

#define BSZ   16
#define NQ    1024
#define NTGT  96
#define NCLS  4
#define DD    6
#define NCOLS (BSZ * NTGT)   // 1536
#define NROWS (BSZ * NQ)     // 16384
#define LHINF 1e9f
#define NHB   16
#define ROWS_PER_BLK 8

typedef float f32x4 __attribute__((ext_vector_type(4)));

// ---------------------------------------------------------------------------
__device__ __forceinline__ float wave_fmin63(float x) {
    const int INF_I = __float_as_int(LHINF);
    int m;
    m = __builtin_amdgcn_update_dpp(INF_I, __float_as_int(x), 0x111, 0xf, 0xf, false);
    x = fminf(x, __int_as_float(m));
    m = __builtin_amdgcn_update_dpp(INF_I, __float_as_int(x), 0x112, 0xf, 0xf, false);
    x = fminf(x, __int_as_float(m));
    m = __builtin_amdgcn_update_dpp(INF_I, __float_as_int(x), 0x114, 0xf, 0xf, false);
    x = fminf(x, __int_as_float(m));
    m = __builtin_amdgcn_update_dpp(INF_I, __float_as_int(x), 0x118, 0xf, 0xf, false);
    x = fminf(x, __int_as_float(m));
    m = __builtin_amdgcn_update_dpp(INF_I, __float_as_int(x), 0x142, 0xf, 0xf, false);
    x = fminf(x, __int_as_float(m));
    m = __builtin_amdgcn_update_dpp(INF_I, __float_as_int(x), 0x143, 0xf, 0xf, false);
    x = fminf(x, __int_as_float(m));
    return x;
}

__device__ __forceinline__ float cost_elem6(const float* bx, const float* tv, float psel) {
    float cd = fabsf(bx[0] - tv[0]);
    cd += fabsf(bx[1] - tv[1]);
    cd += fabsf(bx[2] - tv[2]);
    cd += fabsf(bx[3] - tv[3]);
    cd += fabsf(bx[4] - tv[4]);
    cd += fabsf(bx[5] - tv[5]);
    return cd - psel;
}

// Shared softmax so tws and C agree exactly.
__device__ __forceinline__ float4 softmax4(float4 lg) {
    const float mx = fmaxf(fmaxf(lg.x, lg.y), fmaxf(lg.z, lg.w));
    const float e0 = expf(lg.x - mx), e1 = expf(lg.y - mx);
    const float e2 = expf(lg.z - mx), e3 = expf(lg.w - mx);
    const float s = (e0 + e1) + (e2 + e3);
    return make_float4(e0 / s, e1 / s, e2 / s, e3 / s);
}

// ---------------------------------------------------------------------------
// twsarg: tws[(b*96+t)*1024 + q] = cost(b,q,t); rowminv/rowarg = min/argmin
// over q (first-index tie-break). grid (96,16) x 256 threads, 4 q per thread.
// ---------------------------------------------------------------------------
__global__ __launch_bounds__(256) void twsarg_kernel(
    const float* __restrict__ logits, const float* __restrict__ boxes,
    const int* __restrict__ labels, const float* __restrict__ tgt,
    float* __restrict__ tws, float* __restrict__ rowminv, int* __restrict__ rowarg)
{
    const int t = blockIdx.x;
    const int b = blockIdx.y;
    const int tr = b * NTGT + t;
    float tv[DD];
#pragma unroll
    for (int d = 0; d < DD; ++d) tv[d] = tgt[(size_t)tr * DD + d];
    const int cls = labels[tr];

    const int q4 = threadIdx.x * 4;
    const int row0 = b * NQ + q4;
    const float4* bx4 = (const float4*)(boxes + (size_t)row0 * DD);
    float bv[24];
#pragma unroll
    for (int c = 0; c < 6; ++c) {
        float4 f = bx4[c];
        bv[c * 4] = f.x; bv[c * 4 + 1] = f.y; bv[c * 4 + 2] = f.z; bv[c * 4 + 3] = f.w;
    }
    float o[4];
#pragma unroll
    for (int c = 0; c < 4; ++c) {
        const float4 p = softmax4(((const float4*)logits)[row0 + c]);
        const float ps = (cls == 0) ? p.x : (cls == 1) ? p.y : (cls == 2) ? p.z : p.w;
        o[c] = cost_elem6(bv + c * DD, tv, ps);
    }
    *((float4*)(tws + (size_t)tr * NQ + q4)) = make_float4(o[0], o[1], o[2], o[3]);

    // block min/argmin over 1024 q, first-index ties
    float bvv = o[0]; int bj = q4;
    if (o[1] < bvv) { bvv = o[1]; bj = q4 + 1; }
    if (o[2] < bvv) { bvv = o[2]; bj = q4 + 2; }
    if (o[3] < bvv) { bvv = o[3]; bj = q4 + 3; }
#pragma unroll
    for (int off = 32; off > 0; off >>= 1) {
        const float ov = __shfl_down(bvv, off, 64);
        const int oj = __shfl_down(bj, off, 64);
        if (ov < bvv || (ov == bvv && oj < bj)) { bvv = ov; bj = oj; }
    }
    __shared__ float sv[4];
    __shared__ int sj[4];
    const int w = threadIdx.x >> 6;
    if ((threadIdx.x & 63) == 0) { sv[w] = bvv; sj[w] = bj; }
    __syncthreads();
    if (threadIdx.x == 0) {
        for (int i = 1; i < 4; ++i)
            if (sv[i] < bvv || (sv[i] == bvv && sj[i] < bj)) { bvv = sv[i]; bj = sj[i]; }
        rowminv[tr] = bvv; rowarg[tr] = bj;
    }
}

// Fallback cost kernel (no ws): full C, probs inline.
__global__ __launch_bounds__(384) void cost_kernel_fb(
    const float* __restrict__ logits, const float* __restrict__ boxes,
    const int* __restrict__ labels, const float* __restrict__ tgt,
    float* __restrict__ C)
{
    const int row = blockIdx.x;
    const int tid = threadIdx.x;
    const float4 pr = softmax4(*reinterpret_cast<const float4*>(logits + (size_t)row * NCLS));
    const float prr[4] = {pr.x, pr.y, pr.z, pr.w};
    float bx[DD];
#pragma unroll
    for (int d = 0; d < DD; ++d) bx[d] = boxes[(size_t)row * DD + d];
    const int colbase = tid * 4;
    const int4 lb = *reinterpret_cast<const int4*>(labels + colbase);
    const int cls[4] = {lb.x, lb.y, lb.z, lb.w};
    float tv[24];
    const float4* tg = reinterpret_cast<const float4*>(tgt + (size_t)colbase * DD);
#pragma unroll
    for (int d = 0; d < 6; ++d) {
        const float4 t4 = tg[d];
        tv[d * 4] = t4.x; tv[d * 4 + 1] = t4.y; tv[d * 4 + 2] = t4.z; tv[d * 4 + 3] = t4.w;
    }
    float o[4];
#pragma unroll
    for (int c = 0; c < 4; ++c) {
        const int cl = cls[c];
        const float ps = (cl == 0) ? prr[0] : (cl == 1) ? prr[1] : (cl == 2) ? prr[2] : prr[3];
        o[c] = cost_elem6(bx, tv + c * DD, ps);
    }
    *reinterpret_cast<float4*>(C + (size_t)row * NCOLS + colbase) =
        make_float4(o[0], o[1], o[2], o[3]);
}

// ---------------------------------------------------------------------------
// Fused: blocks 0..15 hungarian (1 wave, parallel greedy + tree-min Dijkstra),
// blocks 16.. build C, 8 rows per block, columns held in registers.
// ---------------------------------------------------------------------------
__global__ __launch_bounds__(384) void fused_kernel(
    const float* __restrict__ tws, const float* __restrict__ logits,
    const float* __restrict__ boxes, const int* __restrict__ labels,
    const float* __restrict__ tgt,
    const float* __restrict__ rowminv, const int* __restrict__ rowarg,
    float* __restrict__ C, float* __restrict__ out_match, int warm)
{
    // ~13.6KB static LDS -> C-blocks keep 5 blocks/CU (wave-limited)
    __shared__ float u_lds[NTGT + 1];
    __shared__ int   p_lds[NQ];
    __shared__ float dmark[NQ];
    __shared__ int   col_own[NQ];      // atomicMin greedy arbitration
    __shared__ int   ja_s[NTGT];
    __shared__ float um_s[NTGT];
    __shared__ int   pendf[NTGT];

    if (blockIdx.x >= NHB) {
        const int rb = (blockIdx.x - NHB) * ROWS_PER_BLK;
        const int tid = threadIdx.x;            // 0..383, owns 4 columns
        const int colbase = tid * 4;
        const int4 lb = ((const int4*)labels)[tid];
        const int cls[4] = {lb.x, lb.y, lb.z, lb.w};
        const float4* tg = (const float4*)(tgt + (size_t)colbase * DD);
        float tv[24];
#pragma unroll
        for (int c = 0; c < 6; ++c) {
            float4 f = tg[c];
            tv[c * 4] = f.x; tv[c * 4 + 1] = f.y; tv[c * 4 + 2] = f.z; tv[c * 4 + 3] = f.w;
        }
#pragma unroll
        for (int r = 0; r < ROWS_PER_BLK; ++r) {
            const int row = rb + r;
            const float4 pr = softmax4(((const float4*)logits)[row]);
            const float prr[4] = {pr.x, pr.y, pr.z, pr.w};
            const float* bp = boxes + (size_t)row * DD;   // block-uniform
            float bx[DD];
#pragma unroll
            for (int d = 0; d < DD; ++d) bx[d] = bp[d];
            float o[4];
#pragma unroll
            for (int c = 0; c < 4; ++c) {
                const int cl = cls[c];
                const float ps = (cl == 0) ? prr[0] : (cl == 1) ? prr[1]
                               : (cl == 2) ? prr[2] : prr[3];
                o[c] = cost_elem6(bx, tv + c * DD, ps);
            }
            f32x4 ov;
            ov.x = o[0]; ov.y = o[1]; ov.z = o[2]; ov.w = o[3];
            __builtin_nontemporal_store(
                ov, (f32x4*)(C + (size_t)row * NCOLS + colbase));
        }
        return;
    }

    // ---- Hungarian: one wave per batch ----
    if (threadIdx.x >= 64) return;
    __builtin_amdgcn_s_setprio(2);
    const int b = blockIdx.x;
    const int lane = threadIdx.x;

    for (int i = lane; i < NQ; i += 64) { p_lds[i] = 0; col_own[i] = 0x7fffffff; }
    for (int i = lane; i < NTGT + 1; i += 64) u_lds[i] = 0.f;
    __builtin_amdgcn_wave_barrier();

    const int jbase = lane * 16;
    const float* Tb = tws + (size_t)b * NTGT * NQ;
    const float* Cstr = C + (size_t)b * NQ * NCOLS + b * NTGT;

    float v[16], Msel[16], msk[16];
    int way[16], p_reg[16];
#pragma unroll
    for (int k = 0; k < 16; ++k) v[k] = 0.f;   // v = 0: rectangular CS holds

    if (warm) {
        // ---- parallel greedy warm start (exact first-t-wins semantics):
        // winner of column j = min t with rowarg[t]==j  (== serial order). ----
        for (int t = lane; t < NTGT; t += 64) {
            ja_s[t] = rowarg[b * NTGT + t];
            um_s[t] = rowminv[b * NTGT + t];
        }
        __builtin_amdgcn_wave_barrier();
        for (int t = lane; t < NTGT; t += 64)
            atomicMin(&col_own[ja_s[t]], t);
        __builtin_amdgcn_wave_barrier();
        for (int t = lane; t < NTGT; t += 64) {
            const int jt = ja_s[t];
            if (col_own[jt] == t) {
                p_lds[jt] = t + 1;
                u_lds[t + 1] = um_s[t];
                pendf[t] = 0;
            } else {
                pendf[t] = 1;
            }
        }
        __builtin_amdgcn_wave_barrier();
    } else {
        for (int t = lane; t < NTGT; t += 64) pendf[t] = 1;
        __builtin_amdgcn_wave_barrier();
    }

    // ---- Dijkstra only for pending rows (R2-verified machinery; direct
    //      coalesced tws row reads, no barriers in the inner loop) ----
    for (int tt = 0; tt < NTGT; ++tt) {
        const int pending = __builtin_amdgcn_readfirstlane(pendf[tt]);
        if (!pending) continue;
        const int i = tt + 1;

        const int4* pl4 = (const int4*)(p_lds + jbase);
#pragma unroll
        for (int c = 0; c < 4; ++c) {
            int4 pp = pl4[c];
            p_reg[c * 4] = pp.x; p_reg[c * 4 + 1] = pp.y;
            p_reg[c * 4 + 2] = pp.z; p_reg[c * 4 + 3] = pp.w;
        }
#pragma unroll
        for (int k = 0; k < 16; ++k) { Msel[k] = LHINF; msk[k] = -LHINF; way[k] = 0; }
        unsigned used = 0u;
        int i0 = i; float Delta = 0.f; int j0cur = 0;
        bool domark = false; int markk = 0;
        float Dfinal = 0.f; int jfreem1 = 0;

        for (;;) {
            float av[16];
            if (warm) {
                const float4* rp = (const float4*)(Tb + (size_t)(i0 - 1) * NQ + jbase);
#pragma unroll
                for (int c = 0; c < 4; ++c) {
                    float4 f = rp[c];
                    av[c * 4] = f.x; av[c * 4 + 1] = f.y;
                    av[c * 4 + 2] = f.z; av[c * 4 + 3] = f.w;
                }
            } else {
                const float* cp = Cstr + (i0 - 1);
#pragma unroll
                for (int k = 0; k < 16; ++k) av[k] = cp[(size_t)(jbase + k) * NCOLS];
            }
            const float u_i0 = u_lds[i0];

#pragma unroll
            for (int k = 0; k < 16; ++k) {
                const bool mk = domark && (markk == k);
                Msel[k] = mk ? LHINF : Msel[k];
                msk[k]  = mk ? LHINF : msk[k];
            }
            used |= (domark ? (1u << markk) : 0u);

            const float c0 = Delta - u_i0;
            // elementwise update (independent per k, parallel-issuable)
#pragma unroll
            for (int k = 0; k < 16; ++k) {
                float cand = (av[k] - v[k]) + c0;
                cand = fmaxf(cand, msk[k]);
                const bool better = cand < Msel[k];
                way[k]  = better ? j0cur : way[k];
                Msel[k] = better ? cand : Msel[k];
            }
            // tree-min with explicit (val,idx) tie-break == first-k semantics
            float tv_[16]; int tk_[16], tp_[16];
#pragma unroll
            for (int k = 0; k < 16; ++k) { tv_[k] = Msel[k]; tk_[k] = k; tp_[k] = p_reg[k]; }
#pragma unroll
            for (int s = 8; s > 0; s >>= 1) {
#pragma unroll
                for (int k = 0; k < 16; ++k) {
                    if (k < s) {
                        const bool r = (tv_[k + s] < tv_[k]) ||
                                       ((tv_[k + s] == tv_[k]) && (tk_[k + s] < tk_[k]));
                        tv_[k] = r ? tv_[k + s] : tv_[k];
                        tk_[k] = r ? tk_[k + s] : tk_[k];
                        tp_[k] = r ? tp_[k + s] : tp_[k];
                    }
                }
            }
            const float lbv = tv_[0];
            const int   lbk = tk_[0];
            const int   lbp = tp_[0];

            const float red = wave_fmin63(lbv);
            const float gmin = __int_as_float(
                __builtin_amdgcn_readlane(__float_as_int(red), 63));
            const unsigned long long bal = __ballot(lbv == gmin);
            const int W = __builtin_amdgcn_readfirstlane((int)__builtin_ctzll(bal));
            const int lbjm1 = jbase + lbk;
            const int j1m1 = __builtin_amdgcn_readlane(lbjm1, W);
            const int i0n  = __builtin_amdgcn_readlane(lbp, W);
            const bool iswin = (lane == W);
            if (iswin) dmark[lbjm1] = lbv;
            domark = iswin; markk = lbk;
            if (i0n == 0) { Dfinal = gmin; jfreem1 = j1m1; break; }
            Delta = gmin; i0 = i0n; j0cur = j1m1 + 1;
        }

        __builtin_amdgcn_wave_barrier();
        float dmv[16];
        const float4* dm4 = (const float4*)(dmark + jbase);
#pragma unroll
        for (int c = 0; c < 4; ++c) {
            float4 f = dm4[c];
            dmv[c * 4] = f.x; dmv[c * 4 + 1] = f.y;
            dmv[c * 4 + 2] = f.z; dmv[c * 4 + 3] = f.w;
        }
#pragma unroll
        for (int k = 0; k < 16; ++k) {
            if ((used >> k) & 1u) {
                const float d = Dfinal - dmv[k];
                v[k] -= d;
                u_lds[p_reg[k]] += d;
            }
        }
        if (lane == 0) u_lds[i] += Dfinal;
        __builtin_amdgcn_wave_barrier();

        int j0m1 = jfreem1;
        for (;;) {
            const int kk = j0m1 & 15;
            const int owner = __builtin_amdgcn_readfirstlane(j0m1 >> 4);
            int s0 = (kk & 1) ? way[1]  : way[0];
            int s1 = (kk & 1) ? way[3]  : way[2];
            int s2 = (kk & 1) ? way[5]  : way[4];
            int s3 = (kk & 1) ? way[7]  : way[6];
            int s4 = (kk & 1) ? way[9]  : way[8];
            int s5 = (kk & 1) ? way[11] : way[10];
            int s6 = (kk & 1) ? way[13] : way[12];
            int s7 = (kk & 1) ? way[15] : way[14];
            int t0 = (kk & 2) ? s1 : s0;
            int t1 = (kk & 2) ? s3 : s2;
            int t2 = (kk & 2) ? s5 : s4;
            int t3 = (kk & 2) ? s7 : s6;
            int q0 = (kk & 4) ? t1 : t0;
            int q1 = (kk & 4) ? t3 : t2;
            int wsel = (kk & 8) ? q1 : q0;
            const int jn = __builtin_amdgcn_readlane(wsel, owner);
            const int pv = (jn == 0) ? i : p_lds[jn - 1];
            if (lane == 0) p_lds[j0m1] = pv;
            __builtin_amdgcn_wave_barrier();
            if (jn == 0) break;
            j0m1 = jn - 1;
        }
    }

    for (int t = lane; t < NQ; t += 64) {
        const int r = p_lds[t];
        if (r > 0) out_match[b * NTGT + r - 1] = (float)t;
    }
}

extern "C" void kernel_launch(void* const* d_in, const int* in_sizes, int n_in,
                              void* d_out, int out_size, void* d_ws, size_t ws_size,
                              hipStream_t stream) {
    const float* logits = (const float*)d_in[0];
    const float* boxes  = (const float*)d_in[1];
    const int*   labels = (const int*)d_in[2];
    const float* tgt    = (const float*)d_in[3];

    float* C = (float*)d_out;
    float* out_match = C + (size_t)NROWS * NCOLS;

    const size_t tws_e = (size_t)NCOLS * NQ;      // 1572864
    const size_t rmv_e = (size_t)NCOLS;           // 1536
    const size_t need = (tws_e + rmv_e * 2) * sizeof(float);

    if (d_ws != nullptr && ws_size >= need) {
        float* tws     = (float*)d_ws;
        float* rowminv = tws + tws_e;
        int*   rowarg  = (int*)(rowminv + rmv_e);
        twsarg_kernel<<<dim3(NTGT, BSZ), 256, 0, stream>>>(
            logits, boxes, labels, tgt, tws, rowminv, rowarg);
        fused_kernel<<<NHB + NROWS / ROWS_PER_BLK, 384, 0, stream>>>(
            tws, logits, boxes, labels, tgt, rowminv, rowarg, C, out_match, 1);
    } else {
        cost_kernel_fb<<<NROWS, 384, 0, stream>>>(logits, boxes, labels, tgt, C);
        fused_kernel<<<NHB, 64, 0, stream>>>(
            nullptr, logits, boxes, labels, tgt, nullptr, nullptr, C, out_match, 0);
    }
}

// Round 14
// 167.653 us; speedup vs baseline: 1.4428x; 1.4428x over previous
//
#include <hip/hip_runtime.h>

// HungarianMatcher on MI355X (gfx950).
// Output 0: C (16, 1024, 1536) fp32 cost matrix.
// Output 1: matched_query (16, 96) written as fp32 values.
//
// R10: R9 post-mortem — tree-min's 48 extra live values spilled to scratch
// (VALUBusy 36->21%, occ 13->6.7%, fused 79->140us). Revert to the exact R6c
// structure (75.6us fused, measured): direct coalesced tws reads, LINEAR
// 16-elem scan with scalar accumulators, serial way-walk. Apply ONE change:
// atomicMin parallel greedy (exact first-t-wins == min-t per column) replacing
// the lane-0 serial loop (96 dependent ~120cy LDS round-trips ~10-14us).
// C-write path unchanged (8 rows/blk, NT stores, setprio(2)).

#define BSZ   16
#define NQ    1024
#define NTGT  96
#define NCLS  4
#define DD    6
#define NCOLS (BSZ * NTGT)   // 1536
#define NROWS (BSZ * NQ)     // 16384
#define LHINF 1e9f
#define NHB   16
#define ROWS_PER_BLK 8

typedef float f32x4 __attribute__((ext_vector_type(4)));

// ---------------------------------------------------------------------------
__device__ __forceinline__ float wave_fmin63(float x) {
    const int INF_I = __float_as_int(LHINF);
    int m;
    m = __builtin_amdgcn_update_dpp(INF_I, __float_as_int(x), 0x111, 0xf, 0xf, false);
    x = fminf(x, __int_as_float(m));
    m = __builtin_amdgcn_update_dpp(INF_I, __float_as_int(x), 0x112, 0xf, 0xf, false);
    x = fminf(x, __int_as_float(m));
    m = __builtin_amdgcn_update_dpp(INF_I, __float_as_int(x), 0x114, 0xf, 0xf, false);
    x = fminf(x, __int_as_float(m));
    m = __builtin_amdgcn_update_dpp(INF_I, __float_as_int(x), 0x118, 0xf, 0xf, false);
    x = fminf(x, __int_as_float(m));
    m = __builtin_amdgcn_update_dpp(INF_I, __float_as_int(x), 0x142, 0xf, 0xf, false);
    x = fminf(x, __int_as_float(m));
    m = __builtin_amdgcn_update_dpp(INF_I, __float_as_int(x), 0x143, 0xf, 0xf, false);
    x = fminf(x, __int_as_float(m));
    return x;
}

__device__ __forceinline__ float cost_elem6(const float* bx, const float* tv, float psel) {
    float cd = fabsf(bx[0] - tv[0]);
    cd += fabsf(bx[1] - tv[1]);
    cd += fabsf(bx[2] - tv[2]);
    cd += fabsf(bx[3] - tv[3]);
    cd += fabsf(bx[4] - tv[4]);
    cd += fabsf(bx[5] - tv[5]);
    return cd - psel;
}

// Shared softmax so tws and C agree exactly.
__device__ __forceinline__ float4 softmax4(float4 lg) {
    const float mx = fmaxf(fmaxf(lg.x, lg.y), fmaxf(lg.z, lg.w));
    const float e0 = expf(lg.x - mx), e1 = expf(lg.y - mx);
    const float e2 = expf(lg.z - mx), e3 = expf(lg.w - mx);
    const float s = (e0 + e1) + (e2 + e3);
    return make_float4(e0 / s, e1 / s, e2 / s, e3 / s);
}

// ---------------------------------------------------------------------------
// twsarg: tws[(b*96+t)*1024 + q] = cost(b,q,t); rowminv/rowarg = min/argmin
// over q (first-index tie-break). grid (96,16) x 256 threads, 4 q per thread.
// ---------------------------------------------------------------------------
__global__ __launch_bounds__(256) void twsarg_kernel(
    const float* __restrict__ logits, const float* __restrict__ boxes,
    const int* __restrict__ labels, const float* __restrict__ tgt,
    float* __restrict__ tws, float* __restrict__ rowminv, int* __restrict__ rowarg)
{
    const int t = blockIdx.x;
    const int b = blockIdx.y;
    const int tr = b * NTGT + t;
    float tv[DD];
#pragma unroll
    for (int d = 0; d < DD; ++d) tv[d] = tgt[(size_t)tr * DD + d];
    const int cls = labels[tr];

    const int q4 = threadIdx.x * 4;
    const int row0 = b * NQ + q4;
    const float4* bx4 = (const float4*)(boxes + (size_t)row0 * DD);
    float bv[24];
#pragma unroll
    for (int c = 0; c < 6; ++c) {
        float4 f = bx4[c];
        bv[c * 4] = f.x; bv[c * 4 + 1] = f.y; bv[c * 4 + 2] = f.z; bv[c * 4 + 3] = f.w;
    }
    float o[4];
#pragma unroll
    for (int c = 0; c < 4; ++c) {
        const float4 p = softmax4(((const float4*)logits)[row0 + c]);
        const float ps = (cls == 0) ? p.x : (cls == 1) ? p.y : (cls == 2) ? p.z : p.w;
        o[c] = cost_elem6(bv + c * DD, tv, ps);
    }
    *((float4*)(tws + (size_t)tr * NQ + q4)) = make_float4(o[0], o[1], o[2], o[3]);

    // block min/argmin over 1024 q, first-index ties
    float bvv = o[0]; int bj = q4;
    if (o[1] < bvv) { bvv = o[1]; bj = q4 + 1; }
    if (o[2] < bvv) { bvv = o[2]; bj = q4 + 2; }
    if (o[3] < bvv) { bvv = o[3]; bj = q4 + 3; }
#pragma unroll
    for (int off = 32; off > 0; off >>= 1) {
        const float ov = __shfl_down(bvv, off, 64);
        const int oj = __shfl_down(bj, off, 64);
        if (ov < bvv || (ov == bvv && oj < bj)) { bvv = ov; bj = oj; }
    }
    __shared__ float sv[4];
    __shared__ int sj[4];
    const int w = threadIdx.x >> 6;
    if ((threadIdx.x & 63) == 0) { sv[w] = bvv; sj[w] = bj; }
    __syncthreads();
    if (threadIdx.x == 0) {
        for (int i = 1; i < 4; ++i)
            if (sv[i] < bvv || (sv[i] == bvv && sj[i] < bj)) { bvv = sv[i]; bj = sj[i]; }
        rowminv[tr] = bvv; rowarg[tr] = bj;
    }
}

// Fallback cost kernel (no ws): full C, probs inline.
__global__ __launch_bounds__(384) void cost_kernel_fb(
    const float* __restrict__ logits, const float* __restrict__ boxes,
    const int* __restrict__ labels, const float* __restrict__ tgt,
    float* __restrict__ C)
{
    const int row = blockIdx.x;
    const int tid = threadIdx.x;
    const float4 pr = softmax4(*reinterpret_cast<const float4*>(logits + (size_t)row * NCLS));
    const float prr[4] = {pr.x, pr.y, pr.z, pr.w};
    float bx[DD];
#pragma unroll
    for (int d = 0; d < DD; ++d) bx[d] = boxes[(size_t)row * DD + d];
    const int colbase = tid * 4;
    const int4 lb = *reinterpret_cast<const int4*>(labels + colbase);
    const int cls[4] = {lb.x, lb.y, lb.z, lb.w};
    float tv[24];
    const float4* tg = reinterpret_cast<const float4*>(tgt + (size_t)colbase * DD);
#pragma unroll
    for (int d = 0; d < 6; ++d) {
        const float4 t4 = tg[d];
        tv[d * 4] = t4.x; tv[d * 4 + 1] = t4.y; tv[d * 4 + 2] = t4.z; tv[d * 4 + 3] = t4.w;
    }
    float o[4];
#pragma unroll
    for (int c = 0; c < 4; ++c) {
        const int cl = cls[c];
        const float ps = (cl == 0) ? prr[0] : (cl == 1) ? prr[1] : (cl == 2) ? prr[2] : prr[3];
        o[c] = cost_elem6(bx, tv + c * DD, ps);
    }
    *reinterpret_cast<float4*>(C + (size_t)row * NCOLS + colbase) =
        make_float4(o[0], o[1], o[2], o[3]);
}

// ---------------------------------------------------------------------------
// Fused: blocks 0..15 hungarian (1 wave; atomicMin greedy + R6c Dijkstra),
// blocks 16.. build C, 8 rows per block, columns held in registers.
// ---------------------------------------------------------------------------
__global__ __launch_bounds__(384) void fused_kernel(
    const float* __restrict__ tws, const float* __restrict__ logits,
    const float* __restrict__ boxes, const int* __restrict__ labels,
    const float* __restrict__ tgt,
    const float* __restrict__ rowminv, const int* __restrict__ rowarg,
    float* __restrict__ C, float* __restrict__ out_match, int warm)
{
    if (blockIdx.x >= NHB) {
        const int rb = (blockIdx.x - NHB) * ROWS_PER_BLK;
        const int tid = threadIdx.x;            // 0..383, owns 4 columns
        const int colbase = tid * 4;
        const int4 lb = ((const int4*)labels)[tid];
        const int cls[4] = {lb.x, lb.y, lb.z, lb.w};
        const float4* tg = (const float4*)(tgt + (size_t)colbase * DD);
        float tv[24];
#pragma unroll
        for (int c = 0; c < 6; ++c) {
            float4 f = tg[c];
            tv[c * 4] = f.x; tv[c * 4 + 1] = f.y; tv[c * 4 + 2] = f.z; tv[c * 4 + 3] = f.w;
        }
#pragma unroll
        for (int r = 0; r < ROWS_PER_BLK; ++r) {
            const int row = rb + r;
            const float4 pr = softmax4(((const float4*)logits)[row]);
            const float prr[4] = {pr.x, pr.y, pr.z, pr.w};
            const float* bp = boxes + (size_t)row * DD;   // block-uniform
            float bx[DD];
#pragma unroll
            for (int d = 0; d < DD; ++d) bx[d] = bp[d];
            float o[4];
#pragma unroll
            for (int c = 0; c < 4; ++c) {
                const int cl = cls[c];
                const float ps = (cl == 0) ? prr[0] : (cl == 1) ? prr[1]
                               : (cl == 2) ? prr[2] : prr[3];
                o[c] = cost_elem6(bx, tv + c * DD, ps);
            }
            f32x4 ov;
            ov.x = o[0]; ov.y = o[1]; ov.z = o[2]; ov.w = o[3];
            __builtin_nontemporal_store(
                ov, (f32x4*)(C + (size_t)row * NCOLS + colbase));
        }
        return;
    }

    // ---- Hungarian: one wave per batch ----
    if (threadIdx.x >= 64) return;
    __builtin_amdgcn_s_setprio(2);   // win issue arbitration vs C-write waves
    const int b = blockIdx.x;
    const int lane = threadIdx.x;

    __shared__ float u_lds[NTGT + 1];
    __shared__ int   p_lds[NQ];
    __shared__ float dmark[NQ];
    __shared__ int   col_own[NQ];    // atomicMin greedy arbitration
    __shared__ int   ja_s[NTGT];
    __shared__ float um_s[NTGT];
    __shared__ int   pendf[NTGT];

    for (int t = lane; t < NQ; t += 64) { p_lds[t] = 0; col_own[t] = 0x7fffffff; }
    for (int t = lane; t < NTGT + 1; t += 64) u_lds[t] = 0.f;
    __builtin_amdgcn_wave_barrier();

    const int jbase = lane * 16;
    const float* Tb = tws + (size_t)b * NTGT * NQ;
    const float* Cstr = C + (size_t)b * NQ * NCOLS + b * NTGT;

    float v[16], Msel[16], msk[16];
    int way[16], p_reg[16];
#pragma unroll
    for (int k = 0; k < 16; ++k) v[k] = 0.f;   // v = 0: rectangular CS holds

    if (warm) {
        // ---- parallel greedy warm start (exact first-t-wins semantics):
        // winner of column j = min t with rowarg[t]==j (== serial order). ----
        for (int t = lane; t < NTGT; t += 64) {
            ja_s[t] = rowarg[b * NTGT + t];
            um_s[t] = rowminv[b * NTGT + t];
        }
        __builtin_amdgcn_wave_barrier();
        for (int t = lane; t < NTGT; t += 64)
            atomicMin(&col_own[ja_s[t]], t);
        __builtin_amdgcn_wave_barrier();
        for (int t = lane; t < NTGT; t += 64) {
            const int jt = ja_s[t];
            if (col_own[jt] == t) {
                p_lds[jt] = t + 1;
                u_lds[t + 1] = um_s[t];
                pendf[t] = 0;
            } else {
                pendf[t] = 1;
            }
        }
        __builtin_amdgcn_wave_barrier();
    } else {
        for (int t = lane; t < NTGT; t += 64) pendf[t] = 1;
        __builtin_amdgcn_wave_barrier();
    }

    // ---- Dijkstra only for pending rows (R2-verified machinery, R6c form:
    //      direct coalesced tws reads, linear scan, scalar accumulators) ----
    for (int tt = 0; tt < NTGT; ++tt) {
        const int pending = __builtin_amdgcn_readfirstlane(pendf[tt]);
        if (!pending) continue;
        const int i = tt + 1;

        const int4* pl4 = (const int4*)(p_lds + jbase);
#pragma unroll
        for (int c = 0; c < 4; ++c) {
            int4 pp = pl4[c];
            p_reg[c * 4] = pp.x; p_reg[c * 4 + 1] = pp.y;
            p_reg[c * 4 + 2] = pp.z; p_reg[c * 4 + 3] = pp.w;
        }
#pragma unroll
        for (int k = 0; k < 16; ++k) { Msel[k] = LHINF; msk[k] = -LHINF; way[k] = 0; }
        unsigned used = 0u;
        int i0 = i; float Delta = 0.f; int j0cur = 0;
        bool domark = false; int markk = 0;
        float Dfinal = 0.f; int jfreem1 = 0;

        for (;;) {
            float av[16];
            if (warm) {
                const float4* rp = (const float4*)(Tb + (size_t)(i0 - 1) * NQ + jbase);
#pragma unroll
                for (int c = 0; c < 4; ++c) {
                    float4 f = rp[c];
                    av[c * 4] = f.x; av[c * 4 + 1] = f.y;
                    av[c * 4 + 2] = f.z; av[c * 4 + 3] = f.w;
                }
            } else {
                const float* cp = Cstr + (i0 - 1);
#pragma unroll
                for (int k = 0; k < 16; ++k) av[k] = cp[(size_t)(jbase + k) * NCOLS];
            }
            const float u_i0 = u_lds[i0];

#pragma unroll
            for (int k = 0; k < 16; ++k) {
                const bool mk = domark && (markk == k);
                Msel[k] = mk ? LHINF : Msel[k];
                msk[k]  = mk ? LHINF : msk[k];
            }
            used |= (domark ? (1u << markk) : 0u);

            const float c0 = Delta - u_i0;
            float lbv = LHINF; int lbk = 0; int lbp = 0;
#pragma unroll
            for (int k = 0; k < 16; ++k) {
                float cand = (av[k] - v[k]) + c0;
                cand = fmaxf(cand, msk[k]);
                const bool better = cand < Msel[k];
                way[k]  = better ? j0cur : way[k];
                Msel[k] = better ? cand : Msel[k];
                const bool b2 = Msel[k] < lbv;
                lbv = b2 ? Msel[k] : lbv;
                lbk = b2 ? k : lbk;
                lbp = b2 ? p_reg[k] : lbp;
            }
            const float red = wave_fmin63(lbv);
            const float gmin = __int_as_float(
                __builtin_amdgcn_readlane(__float_as_int(red), 63));
            const unsigned long long bal = __ballot(lbv == gmin);
            const int W = __builtin_amdgcn_readfirstlane((int)__builtin_ctzll(bal));
            const int lbjm1 = jbase + lbk;
            const int j1m1 = __builtin_amdgcn_readlane(lbjm1, W);
            const int i0n  = __builtin_amdgcn_readlane(lbp, W);
            const bool iswin = (lane == W);
            if (iswin) dmark[lbjm1] = lbv;
            domark = iswin; markk = lbk;
            if (i0n == 0) { Dfinal = gmin; jfreem1 = j1m1; break; }
            Delta = gmin; i0 = i0n; j0cur = j1m1 + 1;
        }

        __builtin_amdgcn_wave_barrier();
        float dmv[16];
        const float4* dm4 = (const float4*)(dmark + jbase);
#pragma unroll
        for (int c = 0; c < 4; ++c) {
            float4 f = dm4[c];
            dmv[c * 4] = f.x; dmv[c * 4 + 1] = f.y;
            dmv[c * 4 + 2] = f.z; dmv[c * 4 + 3] = f.w;
        }
#pragma unroll
        for (int k = 0; k < 16; ++k) {
            if ((used >> k) & 1u) {
                const float d = Dfinal - dmv[k];
                v[k] -= d;
                u_lds[p_reg[k]] += d;
            }
        }
        if (lane == 0) u_lds[i] += Dfinal;
        __builtin_amdgcn_wave_barrier();

        int j0m1 = jfreem1;
        for (;;) {
            const int kk = j0m1 & 15;
            const int owner = __builtin_amdgcn_readfirstlane(j0m1 >> 4);
            int s0 = (kk & 1) ? way[1]  : way[0];
            int s1 = (kk & 1) ? way[3]  : way[2];
            int s2 = (kk & 1) ? way[5]  : way[4];
            int s3 = (kk & 1) ? way[7]  : way[6];
            int s4 = (kk & 1) ? way[9]  : way[8];
            int s5 = (kk & 1) ? way[11] : way[10];
            int s6 = (kk & 1) ? way[13] : way[12];
            int s7 = (kk & 1) ? way[15] : way[14];
            int t0 = (kk & 2) ? s1 : s0;
            int t1 = (kk & 2) ? s3 : s2;
            int t2 = (kk & 2) ? s5 : s4;
            int t3 = (kk & 2) ? s7 : s6;
            int q0 = (kk & 4) ? t1 : t0;
            int q1 = (kk & 4) ? t3 : t2;
            int wsel = (kk & 8) ? q1 : q0;
            const int jn = __builtin_amdgcn_readlane(wsel, owner);
            const int pv = (jn == 0) ? i : p_lds[jn - 1];
            if (lane == 0) p_lds[j0m1] = pv;
            __builtin_amdgcn_wave_barrier();
            if (jn == 0) break;
            j0m1 = jn - 1;
        }
    }

    for (int t = lane; t < NQ; t += 64) {
        const int r = p_lds[t];
        if (r > 0) out_match[b * NTGT + r - 1] = (float)t;
    }
}

extern "C" void kernel_launch(void* const* d_in, const int* in_sizes, int n_in,
                              void* d_out, int out_size, void* d_ws, size_t ws_size,
                              hipStream_t stream) {
    const float* logits = (const float*)d_in[0];
    const float* boxes  = (const float*)d_in[1];
    const int*   labels = (const int*)d_in[2];
    const float* tgt    = (const float*)d_in[3];

    float* C = (float*)d_out;
    float* out_match = C + (size_t)NROWS * NCOLS;

    const size_t tws_e = (size_t)NCOLS * NQ;      // 1572864
    const size_t rmv_e = (size_t)NCOLS;           // 1536
    const size_t need = (tws_e + rmv_e * 2) * sizeof(float);

    if (d_ws != nullptr && ws_size >= need) {
        float* tws     = (float*)d_ws;
        float* rowminv = tws + tws_e;
        int*   rowarg  = (int*)(rowminv + rmv_e);
        twsarg_kernel<<<dim3(NTGT, BSZ), 256, 0, stream>>>(
            logits, boxes, labels, tgt, tws, rowminv, rowarg);
        fused_kernel<<<NHB + NROWS / ROWS_PER_BLK, 384, 0, stream>>>(
            tws, logits, boxes, labels, tgt, rowminv, rowarg, C, out_match, 1);
    } else {
        cost_kernel_fb<<<NROWS, 384, 0, stream>>>(logits, boxes, labels, tgt, C);
        fused_kernel<<<NHB, 64, 0, stream>>>(
            nullptr, logits, boxes, labels, tgt, nullptr, nullptr, C, out_match, 0);
    }
}